// Round 7
// baseline (131.814 us; speedup 1.0000x reference)
//
#include <hip/hip_runtime.h>
#include <hip/hip_bf16.h>
#include <math.h>

// SpectralLinear: out = x @ (M_U * diag(sigma) * M_V) + bias
// Compact WY without explicit T:  T^{-1} = strict_upper(G) + diag(1/beta)
//   A = Umat*T_U (forward subst)   R = T_V*Vmat^T (backward subst)
//   C = (Umat^T S) Vmat ;  E = SV - A*C
//   W = S - [A | E] . [SU^T ; R]
// Inputs U,V are already upper-triangular (setup applies jnp.triu):
//   Umat[r,i] = U[i,r], Vmat[r,i] = V[63-i,r].
// out = x @ W + bias via bf16 MFMA (Wt = W^T bf16; fp32 accumulate).
// R5 lesson: NO device-scope spin barriers (~120us coherence-poll tax).
// R7: substitutions moved INTO k_WtE (per-column independent; each block
// computes only the 32 At-columns + 32 R-columns it needs; x16 redundancy is
// free across idle CUs). Launch count 4 -> 3.

#define INSIZE 512
#define NREF 64
#define BATCH 8192

// workspace layout (float slots)
static constexpr int OFF_WT    = 0;                    // 512*512 bf16 = 131072 slots
static constexpr int OFF_SIGMA = 131072;               // 512
static constexpr int OFF_BETAU = OFF_SIGMA + 512;      // 64
static constexpr int OFF_BETAV = OFF_BETAU + 64;       // 64
static constexpr int OFF_GU    = OFF_BETAV + 64;       // 64*64
static constexpr int OFF_GV    = OFF_GU + 4096;        // 64*64
static constexpr int OFF_C     = OFF_GV + 4096;        // 64*64

__device__ inline float sigma_of(float pv) {
    float s = 1.0f / (1.0f + expf(-pv));
    return 0.55f + 0.9f * (s - 0.5f);   // SIGMA_MIN=0.1, SIGMA_MAX=1.0
}

// ---------------------------------------------------------------------------
// k_prep: blocks 0..63   -> G_U row i (+beta_U[i])
//         blocks 64..127 -> G_V row i (+beta_V[i])  (packed order: row 63-i)
//         blocks 128..191-> C row i:  C[i,j] = sum_c U[i,c] sig_c V[63-j,c]
//         block 192      -> sigma array
__global__ __launch_bounds__(256) void k_prep(const float* __restrict__ U,
                                              const float* __restrict__ V,
                                              const float* __restrict__ p,
                                              float* __restrict__ ws) {
    int b = blockIdx.x, t = threadIdx.x;
    if (b == 192) {
        for (int c = t; c < INSIZE; c += 256)
            (ws + OFF_SIGMA)[c] = sigma_of(p[c]);
        return;
    }
    __shared__ float rowi[INSIZE];
    int w = t >> 6, l = t & 63;
    if (b < 128) {
        bool isV = (b >= 64);
        int i = isV ? (b - 64) : b;
        const float* src = isV ? V : U;
        int srow = isV ? (63 - i) : i;
        for (int c = t; c < INSIZE; c += 256) rowi[c] = src[srow * INSIZE + c];
        __syncthreads();
        float* G = ws + (isV ? OFF_GV : OFF_GU);
        float* beta = ws + (isV ? OFF_BETAV : OFF_BETAU);
        for (int jj = 0; jj < 16; ++jj) {
            int j = w * 16 + jj;
            int jrow = isV ? (63 - j) : j;
            const float* rj = src + jrow * INSIZE;
            float s = 0.f;
            for (int c = l; c < INSIZE; c += 64) s += rowi[c] * rj[c];
            for (int o = 32; o > 0; o >>= 1) s += __shfl_down(s, o, 64);
            if (l == 0) {
                G[i * 64 + j] = s;
                if (j == i) beta[i] = 2.0f / s;
            }
        }
    } else {
        int i = b - 128;
        for (int c = t; c < INSIZE; c += 256)
            rowi[c] = U[i * INSIZE + c] * sigma_of(p[c]);
        __syncthreads();
        float* C = ws + OFF_C;
        for (int jj = 0; jj < 16; ++jj) {
            int j = w * 16 + jj;
            const float* rj = V + (63 - j) * INSIZE;
            float s = 0.f;
            for (int c = l; c < INSIZE; c += 64) s += rowi[c] * rj[c];
            for (int o = 32; o > 0; o >>= 1) s += __shfl_down(s, o, 64);
            if (l == 0) C[i * 64 + j] = s;
        }
    }
}

// ---------------------------------------------------------------------------
// Fused substitution + E + W tile + transpose + bf16 cast, per 32x32 tile.
// LDS: Ps[128][34] (At rows 0..63 | Et rows 64..127)
//      Qs[128][34] (SU^T rows 0..63 | R rows 64..127); flat-doubles as G_V stage
//      Xs[4160]    (G_U+beta_U stage, then C)
// Phase b: thread t<32 computes At col r0+t (reads Xs=G_U) -> Ps rows 0..63;
//          thread 32<=t<64 computes R col c0+(t-32) (reads Qs-flat=G_V) -> regs.
// Bitwise-identical arithmetic to the former k_AR.
__global__ __launch_bounds__(256) void k_WtE(const float* __restrict__ U,
                                             const float* __restrict__ V,
                                             float* __restrict__ ws) {
    __shared__ float Ps[128][34];
    __shared__ float Qs[128][34];
    __shared__ float Xs[4160];
    int t = threadIdx.x;
    int r0 = (blockIdx.x >> 4) * 32;
    int c0 = (blockIdx.x & 15) * 32;
    const float* sig = ws + OFF_SIGMA;
    float* Qf = &Qs[0][0];

    // ---- phase a: stage G_U -> Xs, G_V -> Qs(flat); betas at [4096..4159]
    for (int i = t; i < 1024; i += 256) {
        *(float4*)&Xs[i * 4] = *(const float4*)&(ws + OFF_GU)[i * 4];
        *(float4*)&Qf[i * 4] = *(const float4*)&(ws + OFF_GV)[i * 4];
    }
    if (t < 64) {
        Xs[4096 + t] = (ws + OFF_BETAU)[t];
        Qf[4096 + t] = (ws + OFF_BETAV)[t];
    }
    __syncthreads();

    // ---- phase b: register-resident substitutions (64 of 256 threads)
    float partR[64];
    if (t < 32) {
        int r = r0 + t;
        float part[64];
#pragma unroll
        for (int j = 0; j < 64; ++j) part[j] = U[j * INSIZE + r];
#pragma unroll
        for (int m = 0; m < 64; ++m) {
            float am = part[m] * Xs[4096 + m];
            part[m] = am;
#pragma unroll
            for (int j = m + 1; j < 64; ++j)
                part[j] -= am * Xs[m * 64 + j];    // G_U row m, consecutive
        }
#pragma unroll
        for (int j = 0; j < 64; ++j) Ps[j][t] = part[j];
    } else if (t < 64) {
        int c = c0 + (t - 32);
#pragma unroll
        for (int i = 0; i < 64; ++i) partR[i] = V[(63 - i) * INSIZE + c];
#pragma unroll
        for (int i = 63; i >= 0; --i) {
            float s = partR[i];
#pragma unroll
            for (int m = i + 1; m < 64; ++m)
                s -= Qf[i * 64 + m] * partR[m];    // G_V row i, consecutive
            partR[i] = s * Qf[4096 + i];
        }
    }
    __syncthreads();   // G_U/G_V dead; Ps rows 0..63 ready; partR in regs

    // ---- phase c: C -> Xs; Qs rows 0..63 = SU^T tile, rows 64..127 = R tile
    for (int i = t; i < 1024; i += 256)
        *(float4*)&Xs[i * 4] = *(const float4*)&(ws + OFF_C)[i * 4];
    int lr = t & 31, kb = t >> 5;         // kb 0..7
    float sc = sig[c0 + lr];
#pragma unroll
    for (int ii = 0; ii < 8; ++ii) {
        int k = kb + ii * 8;              // 0..63
        Qs[k][lr] = U[k * INSIZE + c0 + lr] * sc;
    }
    if (t >= 32 && t < 64) {
#pragma unroll
        for (int i = 0; i < 64; ++i) Qs[64 + i][t - 32] = partR[i];
    }
    __syncthreads();

    // ---- Et: Ps rows 64..127.  Et[j,r] = sig_r V[63-j,r] - sum_i At[i,r] C[i,j]
    float sr = sig[r0 + lr];
#pragma unroll
    for (int ii = 0; ii < 8; ++ii) {
        int j = kb * 8 + ii;              // 0..63
        float e = sr * V[(63 - j) * INSIZE + r0 + lr];
#pragma unroll 8
        for (int i = 0; i < 64; ++i)
            e -= Ps[i][lr] * Xs[i * 64 + j];
        Ps[64 + j][lr] = e;
    }
    __syncthreads();

    // ---- 32x32x128 tile GEMM, 2x2 per thread; write Wt bf16 (transposed)
    int ty = t >> 4, tx = t & 15;
    float a00 = 0.f, a01 = 0.f, a10 = 0.f, a11 = 0.f;
#pragma unroll
    for (int k = 0; k < 128; ++k) {
        float2 a = *(const float2*)&Ps[k][ty * 2];
        float2 bq = *(const float2*)&Qs[k][tx * 2];
        a00 += a.x * bq.x; a01 += a.x * bq.y;
        a10 += a.y * bq.x; a11 += a.y * bq.y;
    }
    int rg = r0 + ty * 2, cg = c0 + tx * 2;
    float w00 = ((rg == cg) ? sig[rg] : 0.f) - a00;
    float w01 = ((rg == cg + 1) ? sig[rg] : 0.f) - a01;
    float w10 = ((rg + 1 == cg) ? sig[rg + 1] : 0.f) - a10;
    float w11 = ((rg + 1 == cg + 1) ? sig[rg + 1] : 0.f) - a11;
    unsigned short* Wt = (unsigned short*)(ws + OFF_WT);
    __hip_bfloat162 lo = __float22bfloat162_rn(make_float2(w00, w10));
    __hip_bfloat162 hi = __float22bfloat162_rn(make_float2(w01, w11));
    *(__hip_bfloat162*)&Wt[cg * INSIZE + rg] = lo;
    *(__hip_bfloat162*)&Wt[(cg + 1) * INSIZE + rg] = hi;
}

// ---------------------------------------------------------------------------
// out = x @ W + bias : bf16 MFMA, 64x128 block tile, BK=32, 512 blocks (2/CU).
// Validated in R2-R6; unchanged.
//   A: m=lane&15, k=(lane>>4)*8+j ; B: n=lane&15, k=(lane>>4)*8+j
//   C/D: col=lane&15, row=(lane>>4)*4+reg
typedef __attribute__((ext_vector_type(8))) short short8;
typedef __attribute__((ext_vector_type(4))) float float4v;

__global__ __launch_bounds__(256) void k_gemm(const float* __restrict__ X,
                                              const float* __restrict__ ws,
                                              const float* __restrict__ bias,
                                              float* __restrict__ out) {
    __shared__ float As[64 * 32];               // 8 KB, chunk-swizzled
    __shared__ unsigned short Bs[128 * 32];     // 8 KB, chunk-swizzled
    const unsigned short* Wt = (const unsigned short*)(ws + OFF_WT);

    int L = blockIdx.x;              // 0..511
    int inner = L & 7;
    int bn = (L >> 3) & 3;
    int bm = (L >> 5) * 8 + inner;   // 0..127
    int row0 = bm * 64, col0 = bn * 128;

    int t = threadIdx.x;
    int l = t & 63, w = t >> 6;
    int wm = (w & 1) * 32, wn = (w >> 1) * 64;

    float4v acc[2][4] = {};
    int quad = l >> 4;
    int lan = l & 15;

    for (int k0 = 0; k0 < INSIZE; k0 += 32) {
        __syncthreads();
#pragma unroll
        for (int i = 0; i < 2; ++i) {
            int P = i * 256 + t;
            int prow = P >> 3, pc = P & 7;
            int lc = pc ^ (prow & 7);
            const float* g = X + (size_t)(row0 + prow) * INSIZE + k0 + lc * 4;
            __builtin_amdgcn_global_load_lds(
                (const __attribute__((address_space(1))) void*)g,
                (__attribute__((address_space(3))) void*)(As + P * 4), 16, 0, 0);
        }
#pragma unroll
        for (int i = 0; i < 2; ++i) {
            int P = i * 256 + t;
            int prow = P >> 2, pc = P & 3;
            int lc = pc ^ ((prow >> 1) & 3);
            const unsigned short* g = Wt + (size_t)(col0 + prow) * INSIZE + k0 + lc * 8;
            __builtin_amdgcn_global_load_lds(
                (const __attribute__((address_space(1))) void*)g,
                (__attribute__((address_space(3))) void*)(Bs + P * 8), 16, 0, 0);
        }
        __syncthreads();

        short8 af[2];
        short8 bf[4];
#pragma unroll
        for (int mi = 0; mi < 2; ++mi) {
            int rl = wm + mi * 16 + lan;
            int c0q = quad * 2;
            const float4v lo = *(const float4v*)(As + (rl * 8 + (c0q ^ (rl & 7))) * 4);
            const float4v hi = *(const float4v*)(As + (rl * 8 + ((c0q + 1) ^ (rl & 7))) * 4);
            union { short8 s; __hip_bfloat162 h[4]; } u;
            u.h[0] = __float22bfloat162_rn(make_float2(lo[0], lo[1]));
            u.h[1] = __float22bfloat162_rn(make_float2(lo[2], lo[3]));
            u.h[2] = __float22bfloat162_rn(make_float2(hi[0], hi[1]));
            u.h[3] = __float22bfloat162_rn(make_float2(hi[2], hi[3]));
            af[mi] = u.s;
        }
#pragma unroll
        for (int ni = 0; ni < 4; ++ni) {
            int rn = wn + ni * 16 + lan;
            int c = quad ^ ((rn >> 1) & 3);
            bf[ni] = *(const short8*)(Bs + (rn * 4 + c) * 8);
        }
#pragma unroll
        for (int mi = 0; mi < 2; ++mi)
#pragma unroll
            for (int ni = 0; ni < 4; ++ni)
                acc[mi][ni] = __builtin_amdgcn_mfma_f32_16x16x32_bf16(
                    af[mi], bf[ni], acc[mi][ni], 0, 0, 0);
    }

#pragma unroll
    for (int ni = 0; ni < 4; ++ni) {
        int c = col0 + wn + ni * 16 + lan;
        float bv = bias[c];
#pragma unroll
        for (int mi = 0; mi < 2; ++mi) {
            int rbase = row0 + wm + mi * 16 + quad * 4;
#pragma unroll
            for (int r = 0; r < 4; ++r)
                out[(size_t)(rbase + r) * INSIZE + c] = acc[mi][ni][r] + bv;
        }
    }
}

// ---------------------------------------------------------------------------
extern "C" void kernel_launch(void* const* d_in, const int* in_sizes, int n_in,
                              void* d_out, int out_size, void* d_ws, size_t ws_size,
                              hipStream_t stream) {
    const float* x    = (const float*)d_in[0];
    const float* p    = (const float*)d_in[1];
    const float* U    = (const float*)d_in[2];
    const float* V    = (const float*)d_in[3];
    const float* bias = (const float*)d_in[4];
    float* ws  = (float*)d_ws;
    float* out = (float*)d_out;

    k_prep<<<193, 256, 0, stream>>>(U, V, p, ws);
    k_WtE<<<256, 256, 0, stream>>>(U, V, ws);
    k_gemm<<<512, 256, 0, stream>>>(x, ws, bias, out);
}

// Round 8
// 123.321 us; speedup vs baseline: 1.0689x; 1.0689x over previous
//
#include <hip/hip_runtime.h>
#include <hip/hip_bf16.h>
#include <math.h>

// SpectralLinear: out = x @ (M_U * diag(sigma) * M_V) + bias
// Compact WY without explicit T:  T^{-1} = strict_upper(G) + diag(1/beta)
//   A = Umat*T_U (forward subst)   R = T_V*Vmat^T (backward subst)
//   C = (Umat^T S) Vmat ;  E = SV - A*C
//   W = S - [A | E] . [SU^T ; R]
// Inputs U,V are already upper-triangular (setup applies jnp.triu):
//   Umat[r,i] = U[i,r], Vmat[r,i] = V[63-i,r].
// out = x @ W + bias via bf16 MFMA (Wt = W^T bf16; fp32 accumulate).
// R5 lesson: NO device-scope spin barriers (~120us coherence-poll tax).
// R7 lesson: fusing the serial substitutions into all 256 WtE blocks costs
// more than the launch it saves (serial prologue + VGPR bloat). Keep k_AR.

#define INSIZE 512
#define NREF 64
#define BATCH 8192

// workspace layout (float slots)
static constexpr int OFF_WT    = 0;                    // 512*512 bf16 = 131072 slots
static constexpr int OFF_SIGMA = 131072;               // 512
static constexpr int OFF_BETAU = OFF_SIGMA + 512;      // 64
static constexpr int OFF_BETAV = OFF_BETAU + 64;       // 64
static constexpr int OFF_GU    = OFF_BETAV + 64;       // 64*64
static constexpr int OFF_GV    = OFF_GU + 4096;        // 64*64
static constexpr int OFF_C     = OFF_GV + 4096;        // 64*64
static constexpr int OFF_PT    = OFF_C + 4096;         // 64*512 (At)
static constexpr int OFF_R     = OFF_PT + 128 * 512;   // 64*512

__device__ inline float sigma_of(float pv) {
    float s = 1.0f / (1.0f + expf(-pv));
    return 0.55f + 0.9f * (s - 0.5f);   // SIGMA_MIN=0.1, SIGMA_MAX=1.0
}

// ---------------------------------------------------------------------------
// k_prep: blocks 0..63   -> G_U row i (+beta_U[i])
//         blocks 64..127 -> G_V row i (+beta_V[i])  (packed order: row 63-i)
//         blocks 128..191-> C row i:  C[i,j] = sum_c U[i,c] sig_c V[63-j,c]
//         block 192      -> sigma array
__global__ __launch_bounds__(256) void k_prep(const float* __restrict__ U,
                                              const float* __restrict__ V,
                                              const float* __restrict__ p,
                                              float* __restrict__ ws) {
    int b = blockIdx.x, t = threadIdx.x;
    if (b == 192) {
        for (int c = t; c < INSIZE; c += 256)
            (ws + OFF_SIGMA)[c] = sigma_of(p[c]);
        return;
    }
    __shared__ float rowi[INSIZE];
    int w = t >> 6, l = t & 63;
    if (b < 128) {
        bool isV = (b >= 64);
        int i = isV ? (b - 64) : b;
        const float* src = isV ? V : U;
        int srow = isV ? (63 - i) : i;
        for (int c = t; c < INSIZE; c += 256) rowi[c] = src[srow * INSIZE + c];
        __syncthreads();
        float* G = ws + (isV ? OFF_GV : OFF_GU);
        float* beta = ws + (isV ? OFF_BETAV : OFF_BETAU);
        for (int jj = 0; jj < 16; ++jj) {
            int j = w * 16 + jj;
            int jrow = isV ? (63 - j) : j;
            const float* rj = src + jrow * INSIZE;
            float s = 0.f;
            for (int c = l; c < INSIZE; c += 64) s += rowi[c] * rj[c];
            for (int o = 32; o > 0; o >>= 1) s += __shfl_down(s, o, 64);
            if (l == 0) {
                G[i * 64 + j] = s;
                if (j == i) beta[i] = 2.0f / s;
            }
        }
    } else {
        int i = b - 128;
        for (int c = t; c < INSIZE; c += 256)
            rowi[c] = U[i * INSIZE + c] * sigma_of(p[c]);
        __syncthreads();
        float* C = ws + OFF_C;
        for (int jj = 0; jj < 16; ++jj) {
            int j = w * 16 + jj;
            const float* rj = V + (63 - j) * INSIZE;
            float s = 0.f;
            for (int c = l; c < INSIZE; c += 64) s += rowi[c] * rj[c];
            for (int o = 32; o > 0; o >>= 1) s += __shfl_down(s, o, 64);
            if (l == 0) C[i * 64 + j] = s;
        }
    }
}

// ---------------------------------------------------------------------------
// A and R via register-resident substitution, row-contiguous (b128) LDS reads.
// block 0: At[j, t] = A[t, j]  forward, partial-update form.
// block 1: R[i, t]  backward, gather form (G row i, m>i consecutive).
__global__ __launch_bounds__(512) void k_AR(const float* __restrict__ U,
                                            const float* __restrict__ V,
                                            float* __restrict__ ws) {
    __shared__ float Gs[64 * 64];
    __shared__ float bs[64];
    int z = blockIdx.x;
    int t = threadIdx.x;             // 0..511
    const float* G = ws + (z ? OFF_GV : OFF_GU);
    const float* beta = ws + (z ? OFF_BETAV : OFF_BETAU);
    for (int i = t; i < 1024; i += 512)
        *(float4*)&Gs[i * 4] = *(const float4*)&G[i * 4];
    if (t < 64) bs[t] = beta[t];
    __syncthreads();
    float part[64];
    if (z == 0) {
        float* At = ws + OFF_PT;
#pragma unroll
        for (int j = 0; j < 64; ++j) part[j] = U[j * INSIZE + t];   // coalesced
#pragma unroll
        for (int m = 0; m < 64; ++m) {
            float am = part[m] * bs[m];
            part[m] = am;
#pragma unroll
            for (int j = m + 1; j < 64; ++j)
                part[j] -= am * Gs[m * 64 + j];    // row m, consecutive -> b128
        }
#pragma unroll
        for (int j = 0; j < 64; ++j) At[j * INSIZE + t] = part[j];
    } else {
        float* R = ws + OFF_R;
#pragma unroll
        for (int i = 0; i < 64; ++i) part[i] = V[(63 - i) * INSIZE + t];
#pragma unroll
        for (int i = 63; i >= 0; --i) {
            float s = part[i];
#pragma unroll
            for (int m = i + 1; m < 64; ++m)
                s -= Gs[i * 64 + m] * part[m];     // row i, consecutive -> b128
            part[i] = s * bs[i];
        }
#pragma unroll
        for (int i = 0; i < 64; ++i) R[i * INSIZE + t] = part[i];
    }
}

// ---------------------------------------------------------------------------
// Fused E + W build + transpose + bf16 cast (per 32x32 output tile):
//   Ps rows 0..63  = At tile (loaded)
//   Ps rows 64..127= Et in-LDS: Et[j,r] = sig_r V[63-j,r] - sum_i At[i,r] C[i,j]
//   Q[k,c] = (k<64) ? U[k,c]*sig_c : R[k-64,c]
//   W[r,c] = (r==c)*sig_r - sum_k Ps[k][r]*Qs[k][c];  Wt[c*512+r]=bf16(W[r,c])
__global__ __launch_bounds__(256) void k_WtE(const float* __restrict__ U,
                                             const float* __restrict__ V,
                                             float* __restrict__ ws) {
    __shared__ float Ps[128][34];
    __shared__ float Qs[128][34];
    __shared__ float Cs[4096];
    int t = threadIdx.x;
    int r0 = (blockIdx.x >> 4) * 32;
    int c0 = (blockIdx.x & 15) * 32;
    const float* At = ws + OFF_PT;
    const float* R = ws + OFF_R;
    const float* sig = ws + OFF_SIGMA;
    int lr = t & 31, kb = t >> 5;         // kb 0..7
    float sc = sig[c0 + lr];
#pragma unroll
    for (int ii = 0; ii < 8; ++ii) {
        int k = kb + ii * 8;              // 0..63
        Ps[k][lr] = At[k * INSIZE + r0 + lr];
    }
#pragma unroll
    for (int ii = 0; ii < 16; ++ii) {
        int k = kb + ii * 8;
        Qs[k][lr] = (k < 64) ? U[k * INSIZE + c0 + lr] * sc
                             : R[(k - 64) * INSIZE + c0 + lr];
    }
#pragma unroll
    for (int i = 0; i < 16; ++i) Cs[t + i * 256] = (ws + OFF_C)[t + i * 256];
    __syncthreads();
    float sr = sig[r0 + lr];
#pragma unroll
    for (int ii = 0; ii < 8; ++ii) {
        int j = kb * 8 + ii;              // 0..63
        float e = sr * V[(63 - j) * INSIZE + r0 + lr];
#pragma unroll 8
        for (int i = 0; i < 64; ++i)
            e -= Ps[i][lr] * Cs[i * 64 + j];
        Ps[64 + j][lr] = e;
    }
    __syncthreads();
    int ty = t >> 4, tx = t & 15;
    float a00 = 0.f, a01 = 0.f, a10 = 0.f, a11 = 0.f;
#pragma unroll
    for (int k = 0; k < 128; ++k) {
        float2 a = *(const float2*)&Ps[k][ty * 2];
        float2 bq = *(const float2*)&Qs[k][tx * 2];
        a00 += a.x * bq.x; a01 += a.x * bq.y;
        a10 += a.y * bq.x; a11 += a.y * bq.y;
    }
    int rg = r0 + ty * 2, cg = c0 + tx * 2;
    float w00 = ((rg == cg) ? sig[rg] : 0.f) - a00;
    float w01 = ((rg == cg + 1) ? sig[rg] : 0.f) - a01;
    float w10 = ((rg + 1 == cg) ? sig[rg + 1] : 0.f) - a10;
    float w11 = ((rg + 1 == cg + 1) ? sig[rg + 1] : 0.f) - a11;
    unsigned short* Wt = (unsigned short*)(ws + OFF_WT);
    __hip_bfloat162 lo = __float22bfloat162_rn(make_float2(w00, w10));
    __hip_bfloat162 hi = __float22bfloat162_rn(make_float2(w01, w11));
    *(__hip_bfloat162*)&Wt[cg * INSIZE + rg] = lo;
    *(__hip_bfloat162*)&Wt[(cg + 1) * INSIZE + rg] = hi;
}

// ---------------------------------------------------------------------------
// out = x @ W + bias : bf16 MFMA, 64x64 block tile, BK=32, 1024 blocks
// (4 blocks/CU -- R6's 512-block grid was grid-limited at 2/CU; more
// co-resident blocks hide the global_load_lds barrier drain).
// Same validated swizzles/fragment layouts as R2-R6.
//   A: m=lane&15, k=(lane>>4)*8+j ; B: n=lane&15, k=(lane>>4)*8+j
//   C/D: col=lane&15, row=(lane>>4)*4+reg
typedef __attribute__((ext_vector_type(8))) short short8;
typedef __attribute__((ext_vector_type(4))) float float4v;

__global__ __launch_bounds__(256) void k_gemm(const float* __restrict__ X,
                                              const float* __restrict__ ws,
                                              const float* __restrict__ bias,
                                              float* __restrict__ out) {
    __shared__ float As[64 * 32];               // 8 KB, chunk-swizzled
    __shared__ unsigned short Bs[64 * 32];      // 4 KB, chunk-swizzled
    const unsigned short* Wt = (const unsigned short*)(ws + OFF_WT);

    // blocks sharing an X row-panel (same bm) share L%8 -> same XCD L2.
    int L = blockIdx.x;              // 0..1023
    int inner = L & 7;
    int bn = (L >> 3) & 7;           // 0..7
    int bm = (L >> 6) * 8 + inner;   // 0..127
    int row0 = bm * 64, col0 = bn * 64;

    int t = threadIdx.x;
    int l = t & 63, w = t >> 6;
    int wm = (w & 1) * 32, wn = (w >> 1) * 32;

    float4v acc[2][2] = {};
    int quad = l >> 4;
    int lan = l & 15;

    for (int k0 = 0; k0 < INSIZE; k0 += 32) {
        __syncthreads();
        // A: 64 rows x 32 k fp32; physical chunk P: prow=P>>3, lc=(P&7)^(prow&7)
#pragma unroll
        for (int i = 0; i < 2; ++i) {
            int P = i * 256 + t;
            int prow = P >> 3, pc = P & 7;
            int lc = pc ^ (prow & 7);
            const float* g = X + (size_t)(row0 + prow) * INSIZE + k0 + lc * 4;
            __builtin_amdgcn_global_load_lds(
                (const __attribute__((address_space(1))) void*)g,
                (__attribute__((address_space(3))) void*)(As + P * 4), 16, 0, 0);
        }
        // B: 64 n-rows x 32 k bf16 from Wt (one 16B inst per thread)
        {
            int P = t;
            int prow = P >> 2, pc = P & 3;
            int lc = pc ^ ((prow >> 1) & 3);
            const unsigned short* g = Wt + (size_t)(col0 + prow) * INSIZE + k0 + lc * 8;
            __builtin_amdgcn_global_load_lds(
                (const __attribute__((address_space(1))) void*)g,
                (__attribute__((address_space(3))) void*)(Bs + P * 8), 16, 0, 0);
        }
        __syncthreads();

        short8 af[2];
        short8 bf[2];
#pragma unroll
        for (int mi = 0; mi < 2; ++mi) {
            int rl = wm + mi * 16 + lan;
            int c0q = quad * 2;
            const float4v lo = *(const float4v*)(As + (rl * 8 + (c0q ^ (rl & 7))) * 4);
            const float4v hi = *(const float4v*)(As + (rl * 8 + ((c0q + 1) ^ (rl & 7))) * 4);
            union { short8 s; __hip_bfloat162 h[4]; } u;
            u.h[0] = __float22bfloat162_rn(make_float2(lo[0], lo[1]));
            u.h[1] = __float22bfloat162_rn(make_float2(lo[2], lo[3]));
            u.h[2] = __float22bfloat162_rn(make_float2(hi[0], hi[1]));
            u.h[3] = __float22bfloat162_rn(make_float2(hi[2], hi[3]));
            af[mi] = u.s;
        }
#pragma unroll
        for (int ni = 0; ni < 2; ++ni) {
            int rn = wn + ni * 16 + lan;
            int c = quad ^ ((rn >> 1) & 3);
            bf[ni] = *(const short8*)(Bs + (rn * 4 + c) * 8);
        }
#pragma unroll
        for (int mi = 0; mi < 2; ++mi)
#pragma unroll
            for (int ni = 0; ni < 2; ++ni)
                acc[mi][ni] = __builtin_amdgcn_mfma_f32_16x16x32_bf16(
                    af[mi], bf[ni], acc[mi][ni], 0, 0, 0);
    }

#pragma unroll
    for (int ni = 0; ni < 2; ++ni) {
        int c = col0 + wn + ni * 16 + lan;
        float bv = bias[c];
#pragma unroll
        for (int mi = 0; mi < 2; ++mi) {
            int rbase = row0 + wm + mi * 16 + quad * 4;
#pragma unroll
            for (int r = 0; r < 4; ++r)
                out[(size_t)(rbase + r) * INSIZE + c] = acc[mi][ni][r] + bv;
        }
    }
}

// ---------------------------------------------------------------------------
extern "C" void kernel_launch(void* const* d_in, const int* in_sizes, int n_in,
                              void* d_out, int out_size, void* d_ws, size_t ws_size,
                              hipStream_t stream) {
    const float* x    = (const float*)d_in[0];
    const float* p    = (const float*)d_in[1];
    const float* U    = (const float*)d_in[2];
    const float* V    = (const float*)d_in[3];
    const float* bias = (const float*)d_in[4];
    float* ws  = (float*)d_ws;
    float* out = (float*)d_out;

    k_prep<<<193, 256, 0, stream>>>(U, V, p, ws);
    k_AR<<<2, 512, 0, stream>>>(U, V, ws);
    k_WtE<<<256, 256, 0, stream>>>(U, V, ws);
    k_gemm<<<1024, 256, 0, stream>>>(x, ws, bias, out);
}

// Round 9
// 113.637 us; speedup vs baseline: 1.1600x; 1.0852x over previous
//
#include <hip/hip_runtime.h>
#include <hip/hip_bf16.h>
#include <math.h>

// SpectralLinear: out = x @ (M_U * diag(sigma) * M_V) + bias
// Compact WY without explicit T:  T^{-1} = strict_upper(G) + diag(1/beta)
//   A = Umat*T_U (forward subst)   R = T_V*Vmat^T (backward subst)
//   C = (Umat^T S) Vmat ;  E = SV - A*C ;  W = S - [A | E] . [SU^T ; R]
// Inputs U,V are already upper-triangular (setup applies jnp.triu).
// R5 lesson: NO device-scope spin barriers. R7 lesson: serial per-column
// substitution inside WtE is too slow. R9: 8-lane-per-column PARALLEL
// recurrence (shfl broadcast + pre-masked G, Gram symmetry kills the
// transpose) -> substitutions fused into k_WtE, launches 4 -> 3.
// out = x @ W + bias via bf16 MFMA (validated R2-R8, unchanged).

#define INSIZE 512
#define NREF 64
#define BATCH 8192

// workspace layout (float slots)
static constexpr int OFF_WT    = 0;                    // 512*512 bf16 = 131072 slots
static constexpr int OFF_SIGMA = 131072;               // 512
static constexpr int OFF_BETAU = OFF_SIGMA + 512;      // 64
static constexpr int OFF_BETAV = OFF_BETAU + 64;       // 64
static constexpr int OFF_GU    = OFF_BETAV + 64;       // 64*64 strict-UPPER masked
static constexpr int OFF_GV    = OFF_GU + 4096;        // 64*64 strict-LOWER masked
static constexpr int OFF_C     = OFF_GV + 4096;        // 64*64

__device__ inline float sigma_of(float pv) {
    float s = 1.0f / (1.0f + expf(-pv));
    return 0.55f + 0.9f * (s - 0.5f);   // SIGMA_MIN=0.1, SIGMA_MAX=1.0
}

// ---------------------------------------------------------------------------
// k_prep: blocks 0..63   -> G_U row i masked j>i (+beta_U[i])
//         blocks 64..127 -> G_V row i masked j<i (+beta_V[i]) (packed: row 63-i)
//         blocks 128..191-> C row i
//         block 192      -> sigma
__global__ __launch_bounds__(256) void k_prep(const float* __restrict__ U,
                                              const float* __restrict__ V,
                                              const float* __restrict__ p,
                                              float* __restrict__ ws) {
    int b = blockIdx.x, t = threadIdx.x;
    if (b == 192) {
        for (int c = t; c < INSIZE; c += 256)
            (ws + OFF_SIGMA)[c] = sigma_of(p[c]);
        return;
    }
    __shared__ float rowi[INSIZE];
    int w = t >> 6, l = t & 63;
    if (b < 128) {
        bool isV = (b >= 64);
        int i = isV ? (b - 64) : b;
        const float* src = isV ? V : U;
        int srow = isV ? (63 - i) : i;
        for (int c = t; c < INSIZE; c += 256) rowi[c] = src[srow * INSIZE + c];
        __syncthreads();
        float* G = ws + (isV ? OFF_GV : OFF_GU);
        float* beta = ws + (isV ? OFF_BETAV : OFF_BETAU);
        for (int jj = 0; jj < 16; ++jj) {
            int j = w * 16 + jj;
            int jrow = isV ? (63 - j) : j;
            const float* rj = src + jrow * INSIZE;
            float s = 0.f;
            for (int c = l; c < INSIZE; c += 64) s += rowi[c] * rj[c];
            for (int o = 32; o > 0; o >>= 1) s += __shfl_down(s, o, 64);
            if (l == 0) {
                bool keep = isV ? (j < i) : (j > i);   // pre-masked triangles
                G[i * 64 + j] = keep ? s : 0.0f;
                if (j == i) beta[i] = 2.0f / s;
            }
        }
    } else {
        int i = b - 128;
        for (int c = t; c < INSIZE; c += 256)
            rowi[c] = U[i * INSIZE + c] * sigma_of(p[c]);
        __syncthreads();
        float* C = ws + OFF_C;
        for (int jj = 0; jj < 16; ++jj) {
            int j = w * 16 + jj;
            const float* rj = V + (63 - j) * INSIZE;
            float s = 0.f;
            for (int c = l; c < INSIZE; c += 64) s += rowi[c] * rj[c];
            for (int o = 32; o > 0; o >>= 1) s += __shfl_down(s, o, 64);
            if (l == 0) C[i * 64 + j] = s;
        }
    }
}

// ---------------------------------------------------------------------------
// Fused: parallel substitutions + E + W tile + transpose + bf16 cast.
// Per 32x32 output tile (256 blocks x 256 threads):
//   phase a: stage masked G_U -> Xs, masked G_V -> Qs(flat), betas appended
//   phase b: 8-lane-per-column recurrences:
//     forward At cols r0..r0+31 -> Ps rows 0..63 (bitwise == R8 k_AR)
//     backward R cols c0..c0+31 -> regs (m-order reversed; fp-equivalent)
//   phase c: C -> Xs; Qs rows 0..63 = SU^T tile, rows 64..127 = R from regs
//   Et: Ps rows 64..127;  then 32x32x128 tile GEMM -> Wt bf16 (transposed)
__global__ __launch_bounds__(256) void k_WtE(const float* __restrict__ U,
                                             const float* __restrict__ V,
                                             float* __restrict__ ws) {
    __shared__ float Ps[128][34];
    __shared__ float Qs[128][34];
    __shared__ float Xs[4160];
    int t = threadIdx.x;
    int r0 = (blockIdx.x >> 4) * 32;
    int c0 = (blockIdx.x & 15) * 32;
    const float* sig = ws + OFF_SIGMA;
    float* Qf = &Qs[0][0];            // 4352 floats; GV+betaV use 4160

    // ---- phase a: stage masked Gram matrices + betas
    for (int i = t; i < 1024; i += 256) {
        *(float4*)&Xs[i * 4] = *(const float4*)&(ws + OFF_GU)[i * 4];
        *(float4*)&Qf[i * 4] = *(const float4*)&(ws + OFF_GV)[i * 4];
    }
    if (t < 64) {
        Xs[4096 + t] = (ws + OFF_BETAU)[t];
        Qf[4096 + t] = (ws + OFF_BETAV)[t];
    }
    __syncthreads();

    // ---- phase b: parallel recurrences. lane l=t&63: column-in-wave l>>3,
    // grp = l&7 owns j = grp*8+jj. All 8 lanes of a column share one wave.
    int l = t & 63;
    int c_loc = (t >> 6) * 8 + (l >> 3);   // 0..31
    int grp = l & 7;
    int srcbase = l & 0x38;
    float pj[8], pr[8];
    {   // forward: At columns r0..r0+31
        int r = r0 + c_loc;
#pragma unroll
        for (int jj = 0; jj < 8; ++jj) pj[jj] = U[(grp * 8 + jj) * INSIZE + r];
#pragma unroll
        for (int m = 0; m < 64; ++m) {
            float tmp = pj[m & 7] * Xs[4096 + m];
            float am = __shfl(tmp, srcbase | (m >> 3), 64);
            if (grp == (m >> 3)) pj[m & 7] = am;
#pragma unroll
            for (int jj = 0; jj < 8; ++jj)
                pj[jj] -= am * Xs[m * 64 + grp * 8 + jj];   // masked: j<=m is 0
        }
#pragma unroll
        for (int jj = 0; jj < 8; ++jj) Ps[grp * 8 + jj][c_loc] = pj[jj];
    }
    {   // backward: R columns c0..c0+31 (G_V symmetric, strict-lower masked)
        int c = c0 + c_loc;
#pragma unroll
        for (int ii = 0; ii < 8; ++ii)
            pr[ii] = V[(63 - (grp * 8 + ii)) * INSIZE + c];
#pragma unroll
        for (int i = 63; i >= 0; --i) {
            float tmp = pr[i & 7] * Qf[4096 + i];
            float ai = __shfl(tmp, srcbase | (i >> 3), 64);
            if (grp == (i >> 3)) pr[i & 7] = ai;
#pragma unroll
            for (int ii = 0; ii < 8; ++ii)
                pr[ii] -= ai * Qf[i * 64 + grp * 8 + ii];   // masked: j>=i is 0
        }
    }
    __syncthreads();   // G_U/G_V dead; Ps rows 0..63 = At tile

    // ---- phase c: C -> Xs; Qs rows 0..63 = SU^T, rows 64..127 = R (from regs)
    for (int i = t; i < 1024; i += 256)
        *(float4*)&Xs[i * 4] = *(const float4*)&(ws + OFF_C)[i * 4];
    int lr = t & 31, kb = t >> 5;         // kb 0..7
    float sc = sig[c0 + lr];
#pragma unroll
    for (int ii = 0; ii < 8; ++ii) {
        int k = kb + ii * 8;              // 0..63
        Qs[k][lr] = U[k * INSIZE + c0 + lr] * sc;
    }
#pragma unroll
    for (int ii = 0; ii < 8; ++ii)
        Qs[64 + grp * 8 + ii][c_loc] = pr[ii];
    __syncthreads();

    // ---- Et: Ps rows 64..127.  Et[j,r] = sig_r V[63-j,r] - sum_i At[i,r] C[i,j]
    float sr = sig[r0 + lr];
#pragma unroll
    for (int ii = 0; ii < 8; ++ii) {
        int j = kb * 8 + ii;              // 0..63
        float e = sr * V[(63 - j) * INSIZE + r0 + lr];
#pragma unroll 8
        for (int i = 0; i < 64; ++i)
            e -= Ps[i][lr] * Xs[i * 64 + j];
        Ps[64 + j][lr] = e;
    }
    __syncthreads();

    // ---- 32x32x128 tile GEMM, 2x2 per thread; write Wt bf16 (transposed)
    int ty = t >> 4, tx = t & 15;
    float a00 = 0.f, a01 = 0.f, a10 = 0.f, a11 = 0.f;
#pragma unroll
    for (int k = 0; k < 128; ++k) {
        float2 a = *(const float2*)&Ps[k][ty * 2];
        float2 bq = *(const float2*)&Qs[k][tx * 2];
        a00 += a.x * bq.x; a01 += a.x * bq.y;
        a10 += a.y * bq.x; a11 += a.y * bq.y;
    }
    int rg = r0 + ty * 2, cg = c0 + tx * 2;
    float w00 = ((rg == cg) ? sig[rg] : 0.f) - a00;
    float w01 = ((rg == cg + 1) ? sig[rg] : 0.f) - a01;
    float w10 = ((rg + 1 == cg) ? sig[rg + 1] : 0.f) - a10;
    float w11 = ((rg + 1 == cg + 1) ? sig[rg + 1] : 0.f) - a11;
    unsigned short* Wt = (unsigned short*)(ws + OFF_WT);
    __hip_bfloat162 lo = __float22bfloat162_rn(make_float2(w00, w10));
    __hip_bfloat162 hi = __float22bfloat162_rn(make_float2(w01, w11));
    *(__hip_bfloat162*)&Wt[cg * INSIZE + rg] = lo;
    *(__hip_bfloat162*)&Wt[(cg + 1) * INSIZE + rg] = hi;
}

// ---------------------------------------------------------------------------
// out = x @ W + bias : bf16 MFMA, 64x64 block tile, BK=32, 1024 blocks
// (4 blocks/CU). Validated R8; unchanged.
//   A: m=lane&15, k=(lane>>4)*8+j ; B: n=lane&15, k=(lane>>4)*8+j
//   C/D: col=lane&15, row=(lane>>4)*4+reg
typedef __attribute__((ext_vector_type(8))) short short8;
typedef __attribute__((ext_vector_type(4))) float float4v;

__global__ __launch_bounds__(256) void k_gemm(const float* __restrict__ X,
                                              const float* __restrict__ ws,
                                              const float* __restrict__ bias,
                                              float* __restrict__ out) {
    __shared__ float As[64 * 32];               // 8 KB, chunk-swizzled
    __shared__ unsigned short Bs[64 * 32];      // 4 KB, chunk-swizzled
    const unsigned short* Wt = (const unsigned short*)(ws + OFF_WT);

    int L = blockIdx.x;              // 0..1023
    int inner = L & 7;
    int bn = (L >> 3) & 7;           // 0..7
    int bm = (L >> 6) * 8 + inner;   // 0..127
    int row0 = bm * 64, col0 = bn * 64;

    int t = threadIdx.x;
    int l = t & 63, w = t >> 6;
    int wm = (w & 1) * 32, wn = (w >> 1) * 32;

    float4v acc[2][2] = {};
    int quad = l >> 4;
    int lan = l & 15;

    for (int k0 = 0; k0 < INSIZE; k0 += 32) {
        __syncthreads();
#pragma unroll
        for (int i = 0; i < 2; ++i) {
            int P = i * 256 + t;
            int prow = P >> 3, pc = P & 7;
            int lc = pc ^ (prow & 7);
            const float* g = X + (size_t)(row0 + prow) * INSIZE + k0 + lc * 4;
            __builtin_amdgcn_global_load_lds(
                (const __attribute__((address_space(1))) void*)g,
                (__attribute__((address_space(3))) void*)(As + P * 4), 16, 0, 0);
        }
        {
            int P = t;
            int prow = P >> 2, pc = P & 3;
            int lc = pc ^ ((prow >> 1) & 3);
            const unsigned short* g = Wt + (size_t)(col0 + prow) * INSIZE + k0 + lc * 8;
            __builtin_amdgcn_global_load_lds(
                (const __attribute__((address_space(1))) void*)g,
                (__attribute__((address_space(3))) void*)(Bs + P * 8), 16, 0, 0);
        }
        __syncthreads();

        short8 af[2];
        short8 bf[2];
#pragma unroll
        for (int mi = 0; mi < 2; ++mi) {
            int rl = wm + mi * 16 + lan;
            int c0q = quad * 2;
            const float4v lo = *(const float4v*)(As + (rl * 8 + (c0q ^ (rl & 7))) * 4);
            const float4v hi = *(const float4v*)(As + (rl * 8 + ((c0q + 1) ^ (rl & 7))) * 4);
            union { short8 s; __hip_bfloat162 h[4]; } u;
            u.h[0] = __float22bfloat162_rn(make_float2(lo[0], lo[1]));
            u.h[1] = __float22bfloat162_rn(make_float2(lo[2], lo[3]));
            u.h[2] = __float22bfloat162_rn(make_float2(hi[0], hi[1]));
            u.h[3] = __float22bfloat162_rn(make_float2(hi[2], hi[3]));
            af[mi] = u.s;
        }
#pragma unroll
        for (int ni = 0; ni < 2; ++ni) {
            int rn = wn + ni * 16 + lan;
            int c = quad ^ ((rn >> 1) & 3);
            bf[ni] = *(const short8*)(Bs + (rn * 4 + c) * 8);
        }
#pragma unroll
        for (int mi = 0; mi < 2; ++mi)
#pragma unroll
            for (int ni = 0; ni < 2; ++ni)
                acc[mi][ni] = __builtin_amdgcn_mfma_f32_16x16x32_bf16(
                    af[mi], bf[ni], acc[mi][ni], 0, 0, 0);
    }

#pragma unroll
    for (int ni = 0; ni < 2; ++ni) {
        int c = col0 + wn + ni * 16 + lan;
        float bv = bias[c];
#pragma unroll
        for (int mi = 0; mi < 2; ++mi) {
            int rbase = row0 + wm + mi * 16 + quad * 4;
#pragma unroll
            for (int r = 0; r < 4; ++r)
                out[(size_t)(rbase + r) * INSIZE + c] = acc[mi][ni][r] + bv;
        }
    }
}

// ---------------------------------------------------------------------------
extern "C" void kernel_launch(void* const* d_in, const int* in_sizes, int n_in,
                              void* d_out, int out_size, void* d_ws, size_t ws_size,
                              hipStream_t stream) {
    const float* x    = (const float*)d_in[0];
    const float* p    = (const float*)d_in[1];
    const float* U    = (const float*)d_in[2];
    const float* V    = (const float*)d_in[3];
    const float* bias = (const float*)d_in[4];
    float* ws  = (float*)d_ws;
    float* out = (float*)d_out;

    k_prep<<<193, 256, 0, stream>>>(U, V, p, ws);
    k_WtE<<<256, 256, 0, stream>>>(U, V, ws);
    k_gemm<<<1024, 256, 0, stream>>>(x, ws, bias, out);
}

// Round 10
// 111.457 us; speedup vs baseline: 1.1826x; 1.0196x over previous
//
#include <hip/hip_runtime.h>
#include <hip/hip_bf16.h>
#include <math.h>

// SpectralLinear: out = x @ (M_U * diag(sigma) * M_V) + bias
// Compact WY without explicit T:  T^{-1} = strict_upper(G) + diag(1/beta)
//   A = Umat*T_U (forward subst)   R = T_V*Vmat^T (backward subst)
//   C = (Umat^T S) Vmat ;  E = SV - A*C ;  W = S - [A | E] . [SU^T ; R]
// Inputs U,V are already upper-triangular (setup applies jnp.triu).
// R5: no device-scope spin barriers. R7: no serial prologue in wide kernels.
// R9: 8-lane parallel recurrences fused into k_WtE (3 launches).
// R10: k_prep register-resident+float4 (no LDS); k_gemm BK=64 (half the
// barrier drains; bitwise-identical accumulation).

#define INSIZE 512
#define NREF 64
#define BATCH 8192

// workspace layout (float slots)
static constexpr int OFF_WT    = 0;                    // 512*512 bf16 = 131072 slots
static constexpr int OFF_SIGMA = 131072;               // 512
static constexpr int OFF_BETAU = OFF_SIGMA + 512;      // 64
static constexpr int OFF_BETAV = OFF_BETAU + 64;       // 64
static constexpr int OFF_GU    = OFF_BETAV + 64;       // 64*64 strict-UPPER masked
static constexpr int OFF_GV    = OFF_GU + 4096;        // 64*64 strict-LOWER masked
static constexpr int OFF_C     = OFF_GV + 4096;        // 64*64

__device__ inline float sigma_of(float pv) {
    float s = 1.0f / (1.0f + expf(-pv));
    return 0.55f + 0.9f * (s - 0.5f);   // SIGMA_MIN=0.1, SIGMA_MAX=1.0
}

__device__ inline float dot8(float4 a0, float4 a1, float4 b0, float4 b1) {
    return a0.x * b0.x + a0.y * b0.y + a0.z * b0.z + a0.w * b0.w
         + a1.x * b1.x + a1.y * b1.y + a1.z * b1.z + a1.w * b1.w;
}

// ---------------------------------------------------------------------------
// k_prep: blocks 0..63   -> G_U row i masked j>i (+beta_U[i])
//         blocks 64..127 -> G_V row i masked j<i (+beta_V[i]) (packed: row 63-i)
//         blocks 128..191-> C row i
//         block 192      -> sigma
// Register-resident: lane l holds its 8 row-i elements (2 float4s) and dots
// against coalesced float4 loads of row j. No LDS, no __syncthreads.
__global__ __launch_bounds__(256) void k_prep(const float* __restrict__ U,
                                              const float* __restrict__ V,
                                              const float* __restrict__ p,
                                              float* __restrict__ ws) {
    int b = blockIdx.x, t = threadIdx.x;
    if (b == 192) {
        for (int c = t; c < INSIZE; c += 256)
            (ws + OFF_SIGMA)[c] = sigma_of(p[c]);
        return;
    }
    int w = t >> 6, l = t & 63;
    float4 b0, b1;
    if (b < 128) {
        bool isV = (b >= 64);
        int i = isV ? (b - 64) : b;
        const float* src = isV ? V : U;
        int srow = isV ? (63 - i) : i;
        const float4* ri4 = (const float4*)(src + srow * INSIZE);
        b0 = ri4[l * 2]; b1 = ri4[l * 2 + 1];
        float* G = ws + (isV ? OFF_GV : OFF_GU);
        float* beta = ws + (isV ? OFF_BETAV : OFF_BETAU);
        for (int jj = 0; jj < 16; ++jj) {
            int j = w * 16 + jj;
            int jrow = isV ? (63 - j) : j;
            const float4* rj4 = (const float4*)(src + jrow * INSIZE);
            float s = dot8(rj4[l * 2], rj4[l * 2 + 1], b0, b1);
            for (int o = 32; o > 0; o >>= 1) s += __shfl_down(s, o, 64);
            if (l == 0) {
                bool keep = isV ? (j < i) : (j > i);   // pre-masked triangles
                G[i * 64 + j] = keep ? s : 0.0f;
                if (j == i) beta[i] = 2.0f / s;
            }
        }
    } else {
        int i = b - 128;
        const float4* ui4 = (const float4*)(U + i * INSIZE);
        const float4* p4 = (const float4*)p;
        float4 u0 = ui4[l * 2], u1 = ui4[l * 2 + 1];
        float4 p0 = p4[l * 2], p1 = p4[l * 2 + 1];
        b0.x = u0.x * sigma_of(p0.x); b0.y = u0.y * sigma_of(p0.y);
        b0.z = u0.z * sigma_of(p0.z); b0.w = u0.w * sigma_of(p0.w);
        b1.x = u1.x * sigma_of(p1.x); b1.y = u1.y * sigma_of(p1.y);
        b1.z = u1.z * sigma_of(p1.z); b1.w = u1.w * sigma_of(p1.w);
        float* C = ws + OFF_C;
        for (int jj = 0; jj < 16; ++jj) {
            int j = w * 16 + jj;
            const float4* rj4 = (const float4*)(V + (63 - j) * INSIZE);
            float s = dot8(rj4[l * 2], rj4[l * 2 + 1], b0, b1);
            for (int o = 32; o > 0; o >>= 1) s += __shfl_down(s, o, 64);
            if (l == 0) C[i * 64 + j] = s;
        }
    }
}

// ---------------------------------------------------------------------------
// Fused: parallel substitutions + E + W tile + transpose + bf16 cast.
// Validated R9; unchanged.
__global__ __launch_bounds__(256) void k_WtE(const float* __restrict__ U,
                                             const float* __restrict__ V,
                                             float* __restrict__ ws) {
    __shared__ float Ps[128][34];
    __shared__ float Qs[128][34];
    __shared__ float Xs[4160];
    int t = threadIdx.x;
    int r0 = (blockIdx.x >> 4) * 32;
    int c0 = (blockIdx.x & 15) * 32;
    const float* sig = ws + OFF_SIGMA;
    float* Qf = &Qs[0][0];

    // ---- phase a: stage masked Gram matrices + betas
    for (int i = t; i < 1024; i += 256) {
        *(float4*)&Xs[i * 4] = *(const float4*)&(ws + OFF_GU)[i * 4];
        *(float4*)&Qf[i * 4] = *(const float4*)&(ws + OFF_GV)[i * 4];
    }
    if (t < 64) {
        Xs[4096 + t] = (ws + OFF_BETAU)[t];
        Qf[4096 + t] = (ws + OFF_BETAV)[t];
    }
    __syncthreads();

    // ---- phase b: 8-lane-per-column parallel recurrences
    int l = t & 63;
    int c_loc = (t >> 6) * 8 + (l >> 3);   // 0..31
    int grp = l & 7;
    int srcbase = l & 0x38;
    float pj[8], pr[8];
    {   // forward: At columns r0..r0+31
        int r = r0 + c_loc;
#pragma unroll
        for (int jj = 0; jj < 8; ++jj) pj[jj] = U[(grp * 8 + jj) * INSIZE + r];
#pragma unroll
        for (int m = 0; m < 64; ++m) {
            float tmp = pj[m & 7] * Xs[4096 + m];
            float am = __shfl(tmp, srcbase | (m >> 3), 64);
            if (grp == (m >> 3)) pj[m & 7] = am;
#pragma unroll
            for (int jj = 0; jj < 8; ++jj)
                pj[jj] -= am * Xs[m * 64 + grp * 8 + jj];   // masked: j<=m is 0
        }
#pragma unroll
        for (int jj = 0; jj < 8; ++jj) Ps[grp * 8 + jj][c_loc] = pj[jj];
    }
    {   // backward: R columns c0..c0+31 (G_V symmetric, strict-lower masked)
        int c = c0 + c_loc;
#pragma unroll
        for (int ii = 0; ii < 8; ++ii)
            pr[ii] = V[(63 - (grp * 8 + ii)) * INSIZE + c];
#pragma unroll
        for (int i = 63; i >= 0; --i) {
            float tmp = pr[i & 7] * Qf[4096 + i];
            float ai = __shfl(tmp, srcbase | (i >> 3), 64);
            if (grp == (i >> 3)) pr[i & 7] = ai;
#pragma unroll
            for (int ii = 0; ii < 8; ++ii)
                pr[ii] -= ai * Qf[i * 64 + grp * 8 + ii];   // masked: j>=i is 0
        }
    }
    __syncthreads();   // G_U/G_V dead; Ps rows 0..63 = At tile

    // ---- phase c: C -> Xs; Qs rows 0..63 = SU^T, rows 64..127 = R (regs)
    for (int i = t; i < 1024; i += 256)
        *(float4*)&Xs[i * 4] = *(const float4*)&(ws + OFF_C)[i * 4];
    int lr = t & 31, kb = t >> 5;         // kb 0..7
    float sc = sig[c0 + lr];
#pragma unroll
    for (int ii = 0; ii < 8; ++ii) {
        int k = kb + ii * 8;              // 0..63
        Qs[k][lr] = U[k * INSIZE + c0 + lr] * sc;
    }
#pragma unroll
    for (int ii = 0; ii < 8; ++ii)
        Qs[64 + grp * 8 + ii][c_loc] = pr[ii];
    __syncthreads();

    // ---- Et: Ps rows 64..127
    float sr = sig[r0 + lr];
#pragma unroll
    for (int ii = 0; ii < 8; ++ii) {
        int j = kb * 8 + ii;              // 0..63
        float e = sr * V[(63 - j) * INSIZE + r0 + lr];
#pragma unroll 8
        for (int i = 0; i < 64; ++i)
            e -= Ps[i][lr] * Xs[i * 64 + j];
        Ps[64 + j][lr] = e;
    }
    __syncthreads();

    // ---- 32x32x128 tile GEMM, 2x2 per thread; write Wt bf16 (transposed)
    int ty = t >> 4, tx = t & 15;
    float a00 = 0.f, a01 = 0.f, a10 = 0.f, a11 = 0.f;
#pragma unroll
    for (int k = 0; k < 128; ++k) {
        float2 a = *(const float2*)&Ps[k][ty * 2];
        float2 bq = *(const float2*)&Qs[k][tx * 2];
        a00 += a.x * bq.x; a01 += a.x * bq.y;
        a10 += a.y * bq.x; a11 += a.y * bq.y;
    }
    int rg = r0 + ty * 2, cg = c0 + tx * 2;
    float w00 = ((rg == cg) ? sig[rg] : 0.f) - a00;
    float w01 = ((rg == cg + 1) ? sig[rg] : 0.f) - a01;
    float w10 = ((rg + 1 == cg) ? sig[rg + 1] : 0.f) - a10;
    float w11 = ((rg + 1 == cg + 1) ? sig[rg + 1] : 0.f) - a11;
    unsigned short* Wt = (unsigned short*)(ws + OFF_WT);
    __hip_bfloat162 lo = __float22bfloat162_rn(make_float2(w00, w10));
    __hip_bfloat162 hi = __float22bfloat162_rn(make_float2(w01, w11));
    *(__hip_bfloat162*)&Wt[cg * INSIZE + rg] = lo;
    *(__hip_bfloat162*)&Wt[(cg + 1) * INSIZE + rg] = hi;
}

// ---------------------------------------------------------------------------
// out = x @ W + bias : bf16 MFMA, 64x64 block tile, BK=64, 1024 blocks
// (4 blocks/CU, 24 KB LDS -> still 4/CU). Half the barrier drains of BK=32;
// k-accumulation order per output unchanged (bitwise-identical result).
//   A: m=lane&15, k=(lane>>4)*8+j ; B: n=lane&15, k=(lane>>4)*8+j
//   C/D: col=lane&15, row=(lane>>4)*4+reg
typedef __attribute__((ext_vector_type(8))) short short8;
typedef __attribute__((ext_vector_type(4))) float float4v;

__global__ __launch_bounds__(256) void k_gemm(const float* __restrict__ X,
                                              const float* __restrict__ ws,
                                              const float* __restrict__ bias,
                                              float* __restrict__ out) {
    __shared__ float As[64 * 64];               // 16 KB, chunk-swizzled (16/row)
    __shared__ unsigned short Bs[64 * 64];      // 8 KB, chunk-swizzled (8/row)
    const unsigned short* Wt = (const unsigned short*)(ws + OFF_WT);

    // blocks sharing an X row-panel (same bm) share L%8 -> same XCD L2.
    int L = blockIdx.x;              // 0..1023
    int inner = L & 7;
    int bn = (L >> 3) & 7;           // 0..7
    int bm = (L >> 6) * 8 + inner;   // 0..127
    int row0 = bm * 64, col0 = bn * 64;

    int t = threadIdx.x;
    int l = t & 63, w = t >> 6;
    int wm = (w & 1) * 32, wn = (w >> 1) * 32;

    float4v acc[2][2] = {};
    int quad = l >> 4;
    int lan = l & 15;

    for (int k0 = 0; k0 < INSIZE; k0 += 64) {
        __syncthreads();
        // A: 64 rows x 64 k fp32 = 1024 16B-chunks; prow=P>>4, lc=(P&15)^(prow&15)
#pragma unroll
        for (int i = 0; i < 4; ++i) {
            int P = i * 256 + t;
            int prow = P >> 4, pc = P & 15;
            int lc = pc ^ (prow & 15);
            const float* g = X + (size_t)(row0 + prow) * INSIZE + k0 + lc * 4;
            __builtin_amdgcn_global_load_lds(
                (const __attribute__((address_space(1))) void*)g,
                (__attribute__((address_space(3))) void*)(As + P * 4), 16, 0, 0);
        }
        // B: 64 rows x 64 k bf16 = 512 16B-chunks; prow=P>>3, lc=(P&7)^(prow&7)
#pragma unroll
        for (int i = 0; i < 2; ++i) {
            int P = i * 256 + t;
            int prow = P >> 3, pc = P & 7;
            int lc = pc ^ (prow & 7);
            const unsigned short* g = Wt + (size_t)(col0 + prow) * INSIZE + k0 + lc * 8;
            __builtin_amdgcn_global_load_lds(
                (const __attribute__((address_space(1))) void*)g,
                (__attribute__((address_space(3))) void*)(Bs + P * 8), 16, 0, 0);
        }
        __syncthreads();

#pragma unroll
        for (int ki = 0; ki < 2; ++ki) {
            short8 af[2];
            short8 bf[2];
#pragma unroll
            for (int mi = 0; mi < 2; ++mi) {
                int rl = wm + mi * 16 + lan;
                int c0q = ki * 8 + quad * 2;
                const float4v lo = *(const float4v*)(As + (rl * 16 + (c0q ^ (rl & 15))) * 4);
                const float4v hi = *(const float4v*)(As + (rl * 16 + ((c0q + 1) ^ (rl & 15))) * 4);
                union { short8 s; __hip_bfloat162 h[4]; } u;
                u.h[0] = __float22bfloat162_rn(make_float2(lo[0], lo[1]));
                u.h[1] = __float22bfloat162_rn(make_float2(lo[2], lo[3]));
                u.h[2] = __float22bfloat162_rn(make_float2(hi[0], hi[1]));
                u.h[3] = __float22bfloat162_rn(make_float2(hi[2], hi[3]));
                af[mi] = u.s;
            }
#pragma unroll
            for (int ni = 0; ni < 2; ++ni) {
                int rn = wn + ni * 16 + lan;
                int c = (ki * 4 + quad) ^ (rn & 7);
                bf[ni] = *(const short8*)(Bs + (rn * 8 + c) * 8);
            }
#pragma unroll
            for (int mi = 0; mi < 2; ++mi)
#pragma unroll
                for (int ni = 0; ni < 2; ++ni)
                    acc[mi][ni] = __builtin_amdgcn_mfma_f32_16x16x32_bf16(
                        af[mi], bf[ni], acc[mi][ni], 0, 0, 0);
        }
    }

#pragma unroll
    for (int ni = 0; ni < 2; ++ni) {
        int c = col0 + wn + ni * 16 + lan;
        float bv = bias[c];
#pragma unroll
        for (int mi = 0; mi < 2; ++mi) {
            int rbase = row0 + wm + mi * 16 + quad * 4;
#pragma unroll
            for (int r = 0; r < 4; ++r)
                out[(size_t)(rbase + r) * INSIZE + c] = acc[mi][ni][r] + bv;
        }
    }
}

// ---------------------------------------------------------------------------
extern "C" void kernel_launch(void* const* d_in, const int* in_sizes, int n_in,
                              void* d_out, int out_size, void* d_ws, size_t ws_size,
                              hipStream_t stream) {
    const float* x    = (const float*)d_in[0];
    const float* p    = (const float*)d_in[1];
    const float* U    = (const float*)d_in[2];
    const float* V    = (const float*)d_in[3];
    const float* bias = (const float*)d_in[4];
    float* ws  = (float*)d_ws;
    float* out = (float*)d_out;

    k_prep<<<193, 256, 0, stream>>>(U, V, p, ws);
    k_WtE<<<256, 256, 0, stream>>>(U, V, ws);
    k_gemm<<<1024, 256, 0, stream>>>(x, ws, bias, out);
}